// Round 8
// baseline (550.909 us; speedup 1.0000x reference)
//
#include <hip/hip_runtime.h>

typedef unsigned short u16;
typedef unsigned int   u32;
typedef unsigned long long u64;

typedef __bf16 bf16_t;
typedef bf16_t bf16x8 __attribute__((ext_vector_type(8)));
typedef float  f32x4  __attribute__((ext_vector_type(4)));

static constexpr int Bz = 4, Sq = 1024, Dm = 1024, Hn = 16, Ff = 4096, Mtok = 4096;
static constexpr int QS = 3072;   // fused qkv row stride

static __device__ __forceinline__ u16 f2bf(float f) {
  u32 u = __builtin_bit_cast(u32, f);
  u32 r = u + 0x7fff + ((u >> 16) & 1);
  return (u16)(r >> 16);
}

static __device__ __forceinline__ void gld16(const u16* g, u16* l) {
  __builtin_amdgcn_global_load_lds((const __attribute__((address_space(1))) u32*)g,
                                   (__attribute__((address_space(3))) u32*)l, 16, 0, 0);
}

// ---------------- fp32 -> bf16 cast ----------------
__global__ void k_cvt(const float* __restrict__ src, u16* __restrict__ dst, int n4) {
  int i = blockIdx.x * 256 + threadIdx.x;
  if (i >= n4) return;
  float4 v = reinterpret_cast<const float4*>(src)[i];
  ushort4 o;
  o.x = f2bf(v.x); o.y = f2bf(v.y); o.z = f2bf(v.z); o.w = f2bf(v.w);
  reinterpret_cast<ushort4*>(dst)[i] = o;
}

// ---------------- mask -> bitmask + row_valid ----------------
__global__ void k_maskpack(const int* __restrict__ mask, u32* __restrict__ mb,
                           u32* __restrict__ rv) {
  int row = blockIdx.x;
  int t = threadIdx.x, w = t >> 6, lane = t & 63;
  const int* mrow = mask + (size_t)row * Sq;
  __shared__ u32 red[4];
  u32 any = 0;
#pragma unroll
  for (int i = 0; i < 4; i++) {
    int chunk = w * 4 + i;
    int k = chunk * 64 + lane;
    u64 bal = __ballot(mrow[k] != 0);
    any |= (u32)(bal | (bal >> 32));
    if (lane == 0) mb[(size_t)row * 32 + chunk * 2]     = (u32)bal;
    if (lane == 1) mb[(size_t)row * 32 + chunk * 2 + 1] = (u32)(bal >> 32);
  }
  if (lane == 0) red[w] = any;
  __syncthreads();
  if (t == 0) rv[row] = (red[0] | red[1] | red[2] | red[3]) ? 1u : 0u;
}

// ---------------- LayerNorm (one block per row) -> bf16 ----------------
__global__ void k_ln(const float* __restrict__ x, const float* __restrict__ g,
                     const float* __restrict__ bb, u16* __restrict__ out) {
  int row = blockIdx.x, t = threadIdx.x;
  float4 v = reinterpret_cast<const float4*>(x + (size_t)row * Dm)[t];
  float s  = v.x + v.y + v.z + v.w;
  float s2 = v.x * v.x + v.y * v.y + v.z * v.z + v.w * v.w;
#pragma unroll
  for (int m = 1; m < 64; m <<= 1) { s += __shfl_xor(s, m); s2 += __shfl_xor(s2, m); }
  __shared__ float rs[4], rs2[4];
  int w = t >> 6;
  if ((t & 63) == 0) { rs[w] = s; rs2[w] = s2; }
  __syncthreads();
  s  = rs[0] + rs[1] + rs[2] + rs[3];
  s2 = rs2[0] + rs2[1] + rs2[2] + rs2[3];
  float mu  = s * (1.0f / Dm);
  float var = s2 * (1.0f / Dm) - mu * mu;
  float r = rsqrtf(var + 1e-5f);
  float4 gv = reinterpret_cast<const float4*>(g)[t];
  float4 bv = reinterpret_cast<const float4*>(bb)[t];
  ushort4 o;
  o.x = f2bf((v.x - mu) * r * gv.x + bv.x);
  o.y = f2bf((v.y - mu) * r * gv.y + bv.y);
  o.z = f2bf((v.z - mu) * r * gv.z + bv.z);
  o.w = f2bf((v.w - mu) * r * gv.w + bv.w);
  reinterpret_cast<ushort4*>(out + (size_t)row * Dm)[t] = o;
}

// ---------------- GEMM 128x128: C[M,N] = A[M,K] * Bw[N,K]^T ----------------
// MODE 0: store bf16
// MODE 2: bf16 out = gelu(acc + bias)
template <int MODE>
__global__ __launch_bounds__(256)
void k_gemm(const u16* __restrict__ A, const u16* __restrict__ Bw,
            int M, int N, int K,
            const float* __restrict__ bias, void* __restrict__ Cout) {
  __shared__ u16 As[128 * 64];
  __shared__ u16 Bs[128 * 64];
  const int t = threadIdx.x;
  const int lane = t & 63, w = t >> 6;
  const int wr = w >> 1, wc = w & 1;
  const int m0 = blockIdx.y * 128, n0 = blockIdx.x * 128;
  const int lr = lane & 15, lk = (lane >> 4) * 8;

  f32x4 acc[4][4] = {};

  for (int kt = 0; kt < K; kt += 64) {
#pragma unroll
    for (int i = 0; i < 4; i++) {
      int cc = i * 256 + t; int row = cc >> 3, c8 = cc & 7;
      gld16(A + (size_t)(m0 + row) * K + kt + c8 * 8, &As[cc * 8]);
    }
#pragma unroll
    for (int i = 0; i < 4; i++) {
      int cc = i * 256 + t; int row = cc >> 3, c8 = cc & 7;
      gld16(Bw + (size_t)(n0 + row) * K + kt + c8 * 8, &Bs[cc * 8]);
    }
    __syncthreads();
#pragma unroll
    for (int kk = 0; kk < 2; kk++) {
      bf16x8 af[4], bfg[4];
#pragma unroll
      for (int m = 0; m < 4; m++)
        af[m] = *reinterpret_cast<const bf16x8*>(&As[(wr * 64 + m * 16 + lr) * 64 + kk * 32 + lk]);
#pragma unroll
      for (int n = 0; n < 4; n++)
        bfg[n] = *reinterpret_cast<const bf16x8*>(&Bs[(wc * 64 + n * 16 + lr) * 64 + kk * 32 + lk]);
#pragma unroll
      for (int m = 0; m < 4; m++)
#pragma unroll
        for (int n = 0; n < 4; n++)
          acc[m][n] = __builtin_amdgcn_mfma_f32_16x16x32_bf16(af[m], bfg[n], acc[m][n], 0, 0, 0);
    }
    __syncthreads();
  }

#pragma unroll
  for (int m = 0; m < 4; m++) {
    const int rowb = m0 + wr * 64 + m * 16 + (lane >> 4) * 4;
#pragma unroll
    for (int n = 0; n < 4; n++) {
      const int col = n0 + wc * 64 + n * 16 + lr;
#pragma unroll
      for (int r = 0; r < 4; r++) {
        const int row = rowb + r;
        float v = acc[m][n][r];
        size_t idx = (size_t)row * N + col;
        if constexpr (MODE == 0) {
          ((u16*)Cout)[idx] = f2bf(v);
        } else {
          float xx = v + bias[col];
          float gl = 0.5f * xx * (1.0f + erff(xx * 0.70710678118f));
          ((u16*)Cout)[idx] = f2bf(gl);
        }
      }
    }
  }
}

// ---------------- GEMM 64x64xBK128 (N=1024 shapes -> 1024 blocks = 4/CU) ------
// XCD-bijective swizzled blockIdx (T1). MODE 1: f32 out = resid + acc
// MODE 3: f32 out = resid + (rv[row] ? acc + bias : 0)
template <int MODE>
__global__ __launch_bounds__(256)
void k_gemm64(const u16* __restrict__ A, const u16* __restrict__ Bw,
              int M, int N, int K,
              const float* __restrict__ resid, const float* __restrict__ bias,
              const u32* __restrict__ rv, float* __restrict__ Cout) {
  __shared__ u16 As[64 * 128];
  __shared__ u16 Bs[64 * 128];
  const int t = threadIdx.x;
  const int lane = t & 63, w = t >> 6;          // wave w owns rows w*16..w*16+15
  // bijective XCD swizzle: nwg % 8 == 0 guaranteed by launch config
  const int nx = gridDim.x;
  const int nwg = nx * gridDim.y;
  const int bid = blockIdx.y * nx + blockIdx.x;
  const int swz = (bid & 7) * (nwg >> 3) + (bid >> 3);
  const int n0 = (swz % nx) * 64, m0 = (swz / nx) * 64;
  const int lr = lane & 15, lk = (lane >> 4) * 8;

  f32x4 acc[4] = {};

  for (int kt = 0; kt < K; kt += 128) {
#pragma unroll
    for (int i = 0; i < 4; i++) {
      int cc = i * 256 + t; int row = cc >> 4, c8 = cc & 15;
      gld16(A + (size_t)(m0 + row) * K + kt + c8 * 8, &As[cc * 8]);
    }
#pragma unroll
    for (int i = 0; i < 4; i++) {
      int cc = i * 256 + t; int row = cc >> 4, c8 = cc & 15;
      gld16(Bw + (size_t)(n0 + row) * K + kt + c8 * 8, &Bs[cc * 8]);
    }
    __syncthreads();
#pragma unroll
    for (int kk = 0; kk < 4; kk++) {
      bf16x8 af = *reinterpret_cast<const bf16x8*>(&As[(w * 16 + lr) * 128 + kk * 32 + lk]);
#pragma unroll
      for (int n = 0; n < 4; n++) {
        bf16x8 bfg = *reinterpret_cast<const bf16x8*>(&Bs[(n * 16 + lr) * 128 + kk * 32 + lk]);
        acc[n] = __builtin_amdgcn_mfma_f32_16x16x32_bf16(af, bfg, acc[n], 0, 0, 0);
      }
    }
    __syncthreads();
  }

  const int rowb = m0 + w * 16 + (lane >> 4) * 4;
#pragma unroll
  for (int n = 0; n < 4; n++) {
    const int col = n0 + n * 16 + lr;
#pragma unroll
    for (int r = 0; r < 4; r++) {
      const int row = rowb + r;
      float v = acc[n][r];
      size_t idx = (size_t)row * N + col;
      if constexpr (MODE == 1) {
        Cout[idx] = resid[idx] + v;
      } else {
        float y = rv[row] ? (v + bias[col]) : 0.0f;
        Cout[idx] = resid[idx] + y;
      }
    }
  }
}

// ---------------- V transpose: qkv V-cols -> vT[bh][d][tok] ----------------
// grid (Sq/64, B*H); 64x64 LDS tile, coalesced 16B on both global sides.
__global__ __launch_bounds__(256)
void k_vtrans(const u16* __restrict__ qkv, u16* __restrict__ vT) {
  __shared__ u16 tile[64 * 72];   // +8 pad breaks bank alignment
  const int t = threadIdx.x;
  const int tt = blockIdx.x;
  const int bh = blockIdx.y, b = bh >> 4, h = bh & 15;
  const u16* src = qkv + (size_t)(b * Sq + tt * 64) * QS + 2048 + h * 64;
#pragma unroll
  for (int j = 0; j < 2; j++) {
    int cc = j * 256 + t, row = cc >> 3, dc0 = (cc & 7) * 8;
    uint4 v = *reinterpret_cast<const uint4*>(src + (size_t)row * QS + dc0);
    *reinterpret_cast<uint4*>(&tile[row * 72 + dc0]) = v;
  }
  __syncthreads();
#pragma unroll
  for (int j = 0; j < 2; j++) {
    int cc = j * 256 + t, d = cc >> 3, tk0 = (cc & 7) * 8;
    u16 tmp[8];
#pragma unroll
    for (int e = 0; e < 8; e++) tmp[e] = tile[(tk0 + e) * 72 + d];
    *reinterpret_cast<uint4*>(vT + (size_t)bh * 65536 + (size_t)d * 1024 + tt * 64 + tk0) =
        *reinterpret_cast<uint4*>(tmp);
  }
}

// ---------------- Flash attention v2 ----------------
// grid (S/64, B*H); 4 waves x 16 q-rows. K and V^T staged via global_load_lds
// with PRE-SWIZZLED global source (linear LDS dest, XOR-swz read), double-buffered.
// Qs is reused as K-buffer 1 after Q moves to registers. LDS = 5*8KB = 40960 B.
__global__ __launch_bounds__(256)
void k_attn(const u16* __restrict__ qkv, const u16* __restrict__ vT,
            const u32* __restrict__ mb, u16* __restrict__ ctxb) {
  __shared__ u16 Qs[4096];    // doubles as K buf 1
  __shared__ u16 Ks0[4096];
  __shared__ u16 Vt0[4096];
  __shared__ u16 Vt1[4096];
  __shared__ u16 Ps[4096];
  const int t = threadIdx.x, lane = t & 63, w = t >> 6;
  const int q0 = blockIdx.x * 64;
  const int bh = blockIdx.y, b = bh >> 4, h = bh & 15;
  const int lr = lane & 15, lkq = (lane >> 4) * 8;

  const size_t qbase = (size_t)(b * Sq + q0) * QS + h * 64;
  const size_t kbase = (size_t)(b * Sq) * QS + 1024 + h * 64;
  const size_t vbase = (size_t)bh * 65536;

  auto stageK = [&](u16* dst, int kt) {
#pragma unroll
    for (int j = 0; j < 2; j++) {
      int cc = j * 256 + t, r = cc >> 3, ch = cc & 7;
      gld16(qkv + kbase + (size_t)(kt * 64 + r) * QS + ((ch ^ (r & 7)) * 8), dst + cc * 8);
    }
  };
  auto stageV = [&](u16* dst, int kt) {
#pragma unroll
    for (int j = 0; j < 2; j++) {
      int cc = j * 256 + t, d = cc >> 3, ch = cc & 7;
      gld16(vT + vbase + (size_t)d * 1024 + kt * 64 + ((ch ^ (d & 7)) * 8), dst + cc * 8);
    }
  };

  // prologue: stage Q + tile 0
  {
#pragma unroll
    for (int j = 0; j < 2; j++) {
      int cc = j * 256 + t, r = cc >> 3, ch = cc & 7;
      gld16(qkv + qbase + (size_t)r * QS + ((ch ^ (r & 7)) * 8), &Qs[cc * 8]);
    }
  }
  stageK(Ks0, 0);
  stageV(Vt0, 0);
  __syncthreads();

  bf16x8 qf[2];
  const int qrow = w * 16 + lr;
#pragma unroll
  for (int kk = 0; kk < 2; kk++)
    qf[kk] = *reinterpret_cast<const bf16x8*>(&Qs[qrow * 64 + ((kk * 32 + lkq) ^ ((qrow & 7) << 3))]);
  __syncthreads();   // Qs now free for reuse as K buf 1

  float m_i[4] = {-1e30f, -1e30f, -1e30f, -1e30f};
  float l_i[4] = {0.f, 0.f, 0.f, 0.f};
  f32x4 accO[4] = {};
  const int rq0 = (lane >> 4) * 4;

  for (int kt = 0; kt < Sq / 64; kt++) {
    u16* kb = (kt & 1) ? Qs : Ks0;
    u16* vb = (kt & 1) ? Vt1 : Vt0;
    if (kt + 1 < Sq / 64) {          // prefetch next tile (in flight across compute)
      stageK((kt & 1) ? Ks0 : Qs, kt + 1);
      stageV((kt & 1) ? Vt0 : Vt1, kt + 1);
    }
    // mask words for this lane's 4 rows (issue early, overlap latency)
    u32 mw0[4], mw1[4];
#pragma unroll
    for (int r = 0; r < 4; r++) {
      int q = q0 + w * 16 + rq0 + r;
      mw0[r] = mb[(size_t)(b * Sq + q) * 32 + kt * 2];
      mw1[r] = mb[(size_t)(b * Sq + q) * 32 + kt * 2 + 1];
    }

    // QK^T
    f32x4 sc[4];
#pragma unroll
    for (int n = 0; n < 4; n++) sc[n] = (f32x4){0.f, 0.f, 0.f, 0.f};
#pragma unroll
    for (int kk = 0; kk < 2; kk++) {
#pragma unroll
      for (int n = 0; n < 4; n++) {
        int krow = n * 16 + lr;
        bf16x8 kf = *reinterpret_cast<const bf16x8*>(
            &kb[krow * 64 + ((kk * 32 + lkq) ^ ((krow & 7) << 3))]);
        sc[n] = __builtin_amdgcn_mfma_f32_16x16x32_bf16(qf[kk], kf, sc[n], 0, 0, 0);
      }
    }

    // scale + mask (fast path when both words all-ones) + row max
    float rmax[4] = {-1e30f, -1e30f, -1e30f, -1e30f};
#pragma unroll
    for (int r = 0; r < 4; r++) {
      if ((mw0[r] & mw1[r]) == 0xffffffffu) {
#pragma unroll
        for (int n = 0; n < 4; n++) {
          float sval = sc[n][r] * 0.125f;
          sc[n][r] = sval;
          rmax[r] = fmaxf(rmax[r], sval);
        }
      } else {
#pragma unroll
        for (int n = 0; n < 4; n++) {
          int kin = n * 16 + lr;
          float sval = sc[n][r] * 0.125f;
          u32 word = (kin & 32) ? mw1[r] : mw0[r];
          if (!((word >> (kin & 31)) & 1)) sval = -1e9f;
          sc[n][r] = sval;
          rmax[r] = fmaxf(rmax[r], sval);
        }
      }
    }
    // 16-lane-group reduce + defer-max (skip rescale when growth <= 8)
#pragma unroll
    for (int r = 0; r < 4; r++) {
#pragma unroll
      for (int mm = 1; mm < 16; mm <<= 1) rmax[r] = fmaxf(rmax[r], __shfl_xor(rmax[r], mm));
      float mnew = fmaxf(m_i[r], rmax[r]);
      if (mnew - m_i[r] > 8.0f) {
        float scale = __expf(m_i[r] - mnew);
        m_i[r] = mnew;
        l_i[r] *= scale;
#pragma unroll
        for (int n = 0; n < 4; n++) accO[n][r] *= scale;
      }
    }
    float rsum[4] = {0.f, 0.f, 0.f, 0.f};
#pragma unroll
    for (int n = 0; n < 4; n++)
#pragma unroll
      for (int r = 0; r < 4; r++) {
        float p = __expf(sc[n][r] - m_i[r]);
        sc[n][r] = p;
        rsum[r] += p;
      }
#pragma unroll
    for (int r = 0; r < 4; r++) {
#pragma unroll
      for (int mm = 1; mm < 16; mm <<= 1) rsum[r] += __shfl_xor(rsum[r], mm);
      l_i[r] += rsum[r];
    }
    // P -> LDS (per-wave private region, swizzled)
#pragma unroll
    for (int n = 0; n < 4; n++)
#pragma unroll
      for (int r = 0; r < 4; r++) {
        int row = rq0 + r;
        Ps[w * 1024 + row * 64 + ((n * 16 + lr) ^ ((row & 7) << 3))] = f2bf(sc[n][r]);
      }
    asm volatile("s_waitcnt lgkmcnt(0)" ::: "memory");
    __builtin_amdgcn_sched_barrier(0);
    // PV
    bf16x8 pf[2];
#pragma unroll
    for (int kk = 0; kk < 2; kk++)
      pf[kk] = *reinterpret_cast<const bf16x8*>(
          &Ps[w * 1024 + lr * 64 + ((kk * 32 + lkq) ^ ((lr & 7) << 3))]);
#pragma unroll
    for (int kk = 0; kk < 2; kk++) {
#pragma unroll
      for (int n = 0; n < 4; n++) {
        int d = n * 16 + lr;
        bf16x8 vf = *reinterpret_cast<const bf16x8*>(
            &vb[d * 64 + ((kk * 32 + lkq) ^ ((d & 7) << 3))]);
        accO[n] = __builtin_amdgcn_mfma_f32_16x16x32_bf16(pf[kk], vf, accO[n], 0, 0, 0);
      }
    }
    __syncthreads();   // drains vmcnt too: next tile's staged data ready
  }

#pragma unroll
  for (int r = 0; r < 4; r++) {
    float recip = (m_i[r] <= -0.9e9f || l_i[r] == 0.f) ? 0.f : 1.f / l_i[r];
    int grow = q0 + w * 16 + rq0 + r;
#pragma unroll
    for (int n = 0; n < 4; n++)
      ctxb[(size_t)(b * Sq + grow) * Dm + h * 64 + n * 16 + lr] = f2bf(accO[n][r] * recip);
  }
}

// ---------------- launch ----------------
extern "C" void kernel_launch(void* const* d_in, const int* in_sizes, int n_in,
                              void* d_out, int out_size, void* d_ws, size_t ws_size,
                              hipStream_t stream) {
  const float* x     = (const float*)d_in[0];
  const float* Wq    = (const float*)d_in[1];
  const float* Wk    = (const float*)d_in[2];
  const float* Wv    = (const float*)d_in[3];
  const float* Wo    = (const float*)d_in[4];
  const float* w1    = (const float*)d_in[5];
  const float* b1    = (const float*)d_in[6];
  const float* w2    = (const float*)d_in[7];
  const float* b2    = (const float*)d_in[8];
  const float* ln1g  = (const float*)d_in[9];
  const float* ln1b  = (const float*)d_in[10];
  const float* ln2g  = (const float*)d_in[11];
  const float* ln2b  = (const float*)d_in[12];
  const int*   mask  = (const int*)d_in[13];
  float* out = (float*)d_out;

  char* ws = (char*)d_ws;
  const size_t MB = 1024 * 1024;
  u16* wqkv_b = (u16*)(ws + 0 * MB);
  u16* wo_b   = (u16*)(ws + 13 * MB / 2);
  u16* w1_b   = (u16*)(ws + 17 * MB / 2);
  u16* w2_b   = (u16*)(ws + 17 * MB);
  u16* h_b    = (u16*)(ws + 51 * MB / 2);
  u32* mbits  = (u32*)(ws + 34 * MB);
  u32* rv     = (u32*)(ws + 34 * MB + 600 * 1024);
  u16* qkv    = (u16*)(ws + 35 * MB);
  u16* ctxb   = (u16*)(ws + 121 * MB / 2);
  u16* vTb    = (u16*)(ws + 69 * MB);
  u16* a1b    = (u16*)(ws + 35 * MB);
  float* x1   = out;   // attention-sublayer result lives in d_out (in-place resid for w2)

  k_cvt<<<1024, 256, 0, stream>>>(Wq, wqkv_b,               262144);
  k_cvt<<<1024, 256, 0, stream>>>(Wk, wqkv_b + 1024 * 1024, 262144);
  k_cvt<<<1024, 256, 0, stream>>>(Wv, wqkv_b + 2048 * 1024, 262144);
  k_cvt<<<1024, 256, 0, stream>>>(Wo, wo_b, 262144);
  k_cvt<<<4096, 256, 0, stream>>>(w1, w1_b, 1048576);
  k_cvt<<<4096, 256, 0, stream>>>(w2, w2_b, 1048576);
  k_maskpack<<<4096, 256, 0, stream>>>(mask, mbits, rv);
  k_ln<<<4096, 256, 0, stream>>>(x, ln1g, ln1b, h_b);

  // fused QKV: M=4096, N=3072, K=1024 -> 768 blocks (3/CU)
  dim3 gqkv(QS / 128, Mtok / 128);
  k_gemm<0><<<gqkv, 256, 0, stream>>>(h_b, wqkv_b, Mtok, QS, Dm, nullptr, qkv);

  // V transpose for attn: 1024 blocks, coalesced both sides
  dim3 gvt(Sq / 64, Bz * Hn);
  k_vtrans<<<gvt, 256, 0, stream>>>(qkv, vTb);

  dim3 ga(Sq / 64, Bz * Hn);
  k_attn<<<ga, 256, 0, stream>>>(qkv, vTb, mbits, ctxb);

  // Wo: M=4096, N=1024, K=1024 -> 64x64 tiles: (16,64) = 1024 blocks (4/CU)
  dim3 gwo(Dm / 64, Mtok / 64);
  k_gemm64<1><<<gwo, 256, 0, stream>>>(ctxb, wo_b, Mtok, Dm, Dm, x, nullptr, nullptr, x1);

  k_ln<<<4096, 256, 0, stream>>>(x1, ln2g, ln2b, h_b);

  // w1: M=4096, N=4096, K=1024 -> 1024 blocks (4/CU)
  dim3 g2(Ff / 128, Mtok / 128);
  k_gemm<2><<<g2, 256, 0, stream>>>(h_b, w1_b, Mtok, Ff, Dm, b1, a1b);

  // w2: M=4096, N=1024, K=4096 -> 64x64 tiles: (16,64) = 1024 blocks (4/CU)
  dim3 gw2(Dm / 64, Mtok / 64);
  k_gemm64<3><<<gw2, 256, 0, stream>>>(a1b, w2_b, Mtok, Dm, Ff, x1, b2, rv, out);
}

// Round 11
// 431.153 us; speedup vs baseline: 1.2778x; 1.2778x over previous
//
#include <hip/hip_runtime.h>

typedef unsigned short u16;
typedef unsigned int   u32;
typedef unsigned long long u64;

typedef __bf16 bf16_t;
typedef bf16_t bf16x8 __attribute__((ext_vector_type(8)));
typedef float  f32x4  __attribute__((ext_vector_type(4)));

static constexpr int Bz = 4, Sq = 1024, Dm = 1024, Hn = 16, Ff = 4096, Mtok = 4096;
static constexpr int QS = 3072;   // fused qkv row stride

static __device__ __forceinline__ u16 f2bf(float f) {
  u32 u = __builtin_bit_cast(u32, f);
  u32 r = u + 0x7fff + ((u >> 16) & 1);
  return (u16)(r >> 16);
}

static __device__ __forceinline__ void gld16(const u16* g, u16* l) {
  __builtin_amdgcn_global_load_lds((const __attribute__((address_space(1))) u32*)g,
                                   (__attribute__((address_space(3))) u32*)l, 16, 0, 0);
}

// ---------------- fp32 -> bf16 cast ----------------
__global__ void k_cvt(const float* __restrict__ src, u16* __restrict__ dst, int n4) {
  int i = blockIdx.x * 256 + threadIdx.x;
  if (i >= n4) return;
  float4 v = reinterpret_cast<const float4*>(src)[i];
  ushort4 o;
  o.x = f2bf(v.x); o.y = f2bf(v.y); o.z = f2bf(v.z); o.w = f2bf(v.w);
  reinterpret_cast<ushort4*>(dst)[i] = o;
}

// ---------------- mask -> bitmask + row_valid ----------------
__global__ void k_maskpack(const int* __restrict__ mask, u32* __restrict__ mb,
                           u32* __restrict__ rv) {
  int row = blockIdx.x;
  int t = threadIdx.x, w = t >> 6, lane = t & 63;
  const int* mrow = mask + (size_t)row * Sq;
  __shared__ u32 red[4];
  u32 any = 0;
#pragma unroll
  for (int i = 0; i < 4; i++) {
    int chunk = w * 4 + i;
    int k = chunk * 64 + lane;
    u64 bal = __ballot(mrow[k] != 0);
    any |= (u32)(bal | (bal >> 32));
    if (lane == 0) mb[(size_t)row * 32 + chunk * 2]     = (u32)bal;
    if (lane == 1) mb[(size_t)row * 32 + chunk * 2 + 1] = (u32)(bal >> 32);
  }
  if (lane == 0) red[w] = any;
  __syncthreads();
  if (t == 0) rv[row] = (red[0] | red[1] | red[2] | red[3]) ? 1u : 0u;
}

// ---------------- LayerNorm (one block per row) -> bf16 ----------------
__global__ void k_ln(const float* __restrict__ x, const float* __restrict__ g,
                     const float* __restrict__ bb, u16* __restrict__ out) {
  int row = blockIdx.x, t = threadIdx.x;
  float4 v = reinterpret_cast<const float4*>(x + (size_t)row * Dm)[t];
  float s  = v.x + v.y + v.z + v.w;
  float s2 = v.x * v.x + v.y * v.y + v.z * v.z + v.w * v.w;
#pragma unroll
  for (int m = 1; m < 64; m <<= 1) { s += __shfl_xor(s, m); s2 += __shfl_xor(s2, m); }
  __shared__ float rs[4], rs2[4];
  int w = t >> 6;
  if ((t & 63) == 0) { rs[w] = s; rs2[w] = s2; }
  __syncthreads();
  s  = rs[0] + rs[1] + rs[2] + rs[3];
  s2 = rs2[0] + rs2[1] + rs2[2] + rs2[3];
  float mu  = s * (1.0f / Dm);
  float var = s2 * (1.0f / Dm) - mu * mu;
  float r = rsqrtf(var + 1e-5f);
  float4 gv = reinterpret_cast<const float4*>(g)[t];
  float4 bv = reinterpret_cast<const float4*>(bb)[t];
  ushort4 o;
  o.x = f2bf((v.x - mu) * r * gv.x + bv.x);
  o.y = f2bf((v.y - mu) * r * gv.y + bv.y);
  o.z = f2bf((v.z - mu) * r * gv.z + bv.z);
  o.w = f2bf((v.w - mu) * r * gv.w + bv.w);
  reinterpret_cast<ushort4*>(out + (size_t)row * Dm)[t] = o;
}

// ---------------- GEMM 128x128: C[M,N] = A[M,K] * Bw[N,K]^T ----------------
// T2 LDS swizzle (pre-swizzled source chunk, XOR'd read) + bijective XCD swizzle.
// MODE 0: store bf16
// MODE 2: bf16 out = gelu(acc + bias)
template <int MODE>
__global__ __launch_bounds__(256)
void k_gemm(const u16* __restrict__ A, const u16* __restrict__ Bw,
            int M, int N, int K,
            const float* __restrict__ bias, void* __restrict__ Cout) {
  __shared__ u16 As[128 * 64];
  __shared__ u16 Bs[128 * 64];
  const int t = threadIdx.x;
  const int lane = t & 63, w = t >> 6;
  const int wr = w >> 1, wc = w & 1;
  // bijective XCD swizzle (nwg % 8 == 0 by launch config)
  const int nx = gridDim.x;
  const int nwg = nx * gridDim.y;
  const int bid = blockIdx.y * nx + blockIdx.x;
  const int swz = (bid & 7) * (nwg >> 3) + (bid >> 3);
  const int m0 = (swz / nx) * 128, n0 = (swz % nx) * 128;
  const int lr = lane & 15, lk = (lane >> 4) * 8;

  f32x4 acc[4][4] = {};

  for (int kt = 0; kt < K; kt += 64) {
#pragma unroll
    for (int i = 0; i < 4; i++) {
      int cc = i * 256 + t; int row = cc >> 3, c8 = cc & 7;
      gld16(A + (size_t)(m0 + row) * K + kt + ((c8 ^ (row & 7)) * 8), &As[cc * 8]);
    }
#pragma unroll
    for (int i = 0; i < 4; i++) {
      int cc = i * 256 + t; int row = cc >> 3, c8 = cc & 7;
      gld16(Bw + (size_t)(n0 + row) * K + kt + ((c8 ^ (row & 7)) * 8), &Bs[cc * 8]);
    }
    __syncthreads();
#pragma unroll
    for (int kk = 0; kk < 2; kk++) {
      bf16x8 af[4], bfg[4];
#pragma unroll
      for (int m = 0; m < 4; m++) {
        int row = wr * 64 + m * 16 + lr;
        af[m] = *reinterpret_cast<const bf16x8*>(
            &As[row * 64 + ((kk * 32 + lk) ^ ((row & 7) << 3))]);
      }
#pragma unroll
      for (int n = 0; n < 4; n++) {
        int row = wc * 64 + n * 16 + lr;
        bfg[n] = *reinterpret_cast<const bf16x8*>(
            &Bs[row * 64 + ((kk * 32 + lk) ^ ((row & 7) << 3))]);
      }
#pragma unroll
      for (int m = 0; m < 4; m++)
#pragma unroll
        for (int n = 0; n < 4; n++)
          acc[m][n] = __builtin_amdgcn_mfma_f32_16x16x32_bf16(af[m], bfg[n], acc[m][n], 0, 0, 0);
    }
    __syncthreads();
  }

#pragma unroll
  for (int m = 0; m < 4; m++) {
    const int rowb = m0 + wr * 64 + m * 16 + (lane >> 4) * 4;
#pragma unroll
    for (int n = 0; n < 4; n++) {
      const int col = n0 + wc * 64 + n * 16 + lr;
#pragma unroll
      for (int r = 0; r < 4; r++) {
        const int row = rowb + r;
        float v = acc[m][n][r];
        size_t idx = (size_t)row * N + col;
        if constexpr (MODE == 0) {
          ((u16*)Cout)[idx] = f2bf(v);
        } else {
          float xx = v + bias[col];
          float gl = 0.5f * xx * (1.0f + erff(xx * 0.70710678118f));
          ((u16*)Cout)[idx] = f2bf(gl);
        }
      }
    }
  }
}

// ---------------- GEMM BM128xBN64xBK64 (N=1024 shapes, R7 geometry) ----------
// + T2 LDS swizzle + bijective XCD swizzle.
// MODE 1: f32 out = resid + acc
// MODE 3: f32 out = resid + (rv[row] ? acc + bias : 0)
template <int MODE>
__global__ __launch_bounds__(256)
void k_gemm64(const u16* __restrict__ A, const u16* __restrict__ Bw,
              int M, int N, int K,
              const float* __restrict__ resid, const float* __restrict__ bias,
              const u32* __restrict__ rv, float* __restrict__ Cout) {
  __shared__ u16 As[128 * 64];
  __shared__ u16 Bs[64 * 64];
  const int t = threadIdx.x;
  const int lane = t & 63, w = t >> 6;           // wave w owns rows w*32..w*32+31
  const int nx = gridDim.x;
  const int nwg = nx * gridDim.y;
  const int bid = blockIdx.y * nx + blockIdx.x;
  const int swz = (bid & 7) * (nwg >> 3) + (bid >> 3);
  const int n0 = (swz % nx) * 64, m0 = (swz / nx) * 128;
  const int lr = lane & 15, lk = (lane >> 4) * 8;

  f32x4 acc[2][4] = {};

  for (int kt = 0; kt < K; kt += 64) {
#pragma unroll
    for (int i = 0; i < 4; i++) {
      int cc = i * 256 + t; int row = cc >> 3, c8 = cc & 7;
      gld16(A + (size_t)(m0 + row) * K + kt + ((c8 ^ (row & 7)) * 8), &As[cc * 8]);
    }
#pragma unroll
    for (int i = 0; i < 2; i++) {
      int cc = i * 256 + t; int row = cc >> 3, c8 = cc & 7;
      gld16(Bw + (size_t)(n0 + row) * K + kt + ((c8 ^ (row & 7)) * 8), &Bs[cc * 8]);
    }
    __syncthreads();
#pragma unroll
    for (int kk = 0; kk < 2; kk++) {
      bf16x8 af[2], bfg[4];
#pragma unroll
      for (int m = 0; m < 2; m++) {
        int row = w * 32 + m * 16 + lr;
        af[m] = *reinterpret_cast<const bf16x8*>(
            &As[row * 64 + ((kk * 32 + lk) ^ ((row & 7) << 3))]);
      }
#pragma unroll
      for (int n = 0; n < 4; n++) {
        int row = n * 16 + lr;
        bfg[n] = *reinterpret_cast<const bf16x8*>(
            &Bs[row * 64 + ((kk * 32 + lk) ^ ((row & 7) << 3))]);
      }
#pragma unroll
      for (int m = 0; m < 2; m++)
#pragma unroll
        for (int n = 0; n < 4; n++)
          acc[m][n] = __builtin_amdgcn_mfma_f32_16x16x32_bf16(af[m], bfg[n], acc[m][n], 0, 0, 0);
    }
    __syncthreads();
  }

#pragma unroll
  for (int m = 0; m < 2; m++) {
    const int rowb = m0 + w * 32 + m * 16 + (lane >> 4) * 4;
#pragma unroll
    for (int n = 0; n < 4; n++) {
      const int col = n0 + n * 16 + lr;
#pragma unroll
      for (int r = 0; r < 4; r++) {
        const int row = rowb + r;
        float v = acc[m][n][r];
        size_t idx = (size_t)row * N + col;
        if constexpr (MODE == 1) {
          Cout[idx] = resid[idx] + v;
        } else {
          float y = rv[row] ? (v + bias[col]) : 0.0f;
          Cout[idx] = resid[idx] + y;
        }
      }
    }
  }
}

// ---------------- V transpose: qkv V-cols -> vT[bh][d][tok] ----------------
// grid (Sq/64, B*H); 64x64 LDS tile, coalesced 16B on both global sides.
__global__ __launch_bounds__(256)
void k_vtrans(const u16* __restrict__ qkv, u16* __restrict__ vT) {
  __shared__ u16 tile[64 * 72];   // +8 pad breaks bank alignment
  const int t = threadIdx.x;
  const int tt = blockIdx.x;
  const int bh = blockIdx.y, b = bh >> 4, h = bh & 15;
  const u16* src = qkv + (size_t)(b * Sq + tt * 64) * QS + 2048 + h * 64;
#pragma unroll
  for (int j = 0; j < 2; j++) {
    int cc = j * 256 + t, row = cc >> 3, dc0 = (cc & 7) * 8;
    uint4 v = *reinterpret_cast<const uint4*>(src + (size_t)row * QS + dc0);
    *reinterpret_cast<uint4*>(&tile[row * 72 + dc0]) = v;
  }
  __syncthreads();
#pragma unroll
  for (int j = 0; j < 2; j++) {
    int cc = j * 256 + t, d = cc >> 3, tk0 = (cc & 7) * 8;
    u16 tmp[8];
#pragma unroll
    for (int e = 0; e < 8; e++) tmp[e] = tile[(tk0 + e) * 72 + d];
    *reinterpret_cast<uint4*>(vT + (size_t)bh * 65536 + (size_t)d * 1024 + tt * 64 + tk0) =
        *reinterpret_cast<uint4*>(tmp);
  }
}

// ---------------- Flash attention v2 ----------------
// grid (S/64, B*H); 4 waves x 16 q-rows. K and V^T staged via global_load_lds
// with PRE-SWIZZLED global source (linear LDS dest, XOR-swz read), double-buffered.
// Qs is reused as K-buffer 1 after Q moves to registers. LDS = 5*8KB = 40960 B.
__global__ __launch_bounds__(256)
void k_attn(const u16* __restrict__ qkv, const u16* __restrict__ vT,
            const u32* __restrict__ mb, u16* __restrict__ ctxb) {
  __shared__ u16 Qs[4096];    // doubles as K buf 1
  __shared__ u16 Ks0[4096];
  __shared__ u16 Vt0[4096];
  __shared__ u16 Vt1[4096];
  __shared__ u16 Ps[4096];
  const int t = threadIdx.x, lane = t & 63, w = t >> 6;
  const int q0 = blockIdx.x * 64;
  const int bh = blockIdx.y, b = bh >> 4, h = bh & 15;
  const int lr = lane & 15, lkq = (lane >> 4) * 8;

  const size_t qbase = (size_t)(b * Sq + q0) * QS + h * 64;
  const size_t kbase = (size_t)(b * Sq) * QS + 1024 + h * 64;
  const size_t vbase = (size_t)bh * 65536;

  auto stageK = [&](u16* dst, int kt) {
#pragma unroll
    for (int j = 0; j < 2; j++) {
      int cc = j * 256 + t, r = cc >> 3, ch = cc & 7;
      gld16(qkv + kbase + (size_t)(kt * 64 + r) * QS + ((ch ^ (r & 7)) * 8), dst + cc * 8);
    }
  };
  auto stageV = [&](u16* dst, int kt) {
#pragma unroll
    for (int j = 0; j < 2; j++) {
      int cc = j * 256 + t, d = cc >> 3, ch = cc & 7;
      gld16(vT + vbase + (size_t)d * 1024 + kt * 64 + ((ch ^ (d & 7)) * 8), dst + cc * 8);
    }
  };

  // prologue: stage Q + tile 0
  {
#pragma unroll
    for (int j = 0; j < 2; j++) {
      int cc = j * 256 + t, r = cc >> 3, ch = cc & 7;
      gld16(qkv + qbase + (size_t)r * QS + ((ch ^ (r & 7)) * 8), &Qs[cc * 8]);
    }
  }
  stageK(Ks0, 0);
  stageV(Vt0, 0);
  __syncthreads();

  bf16x8 qf[2];
  const int qrow = w * 16 + lr;
#pragma unroll
  for (int kk = 0; kk < 2; kk++)
    qf[kk] = *reinterpret_cast<const bf16x8*>(&Qs[qrow * 64 + ((kk * 32 + lkq) ^ ((qrow & 7) << 3))]);
  __syncthreads();   // Qs now free for reuse as K buf 1

  float m_i[4] = {-1e30f, -1e30f, -1e30f, -1e30f};
  float l_i[4] = {0.f, 0.f, 0.f, 0.f};
  f32x4 accO[4] = {};
  const int rq0 = (lane >> 4) * 4;

  for (int kt = 0; kt < Sq / 64; kt++) {
    u16* kb = (kt & 1) ? Qs : Ks0;
    u16* vb = (kt & 1) ? Vt1 : Vt0;
    if (kt + 1 < Sq / 64) {          // prefetch next tile (in flight across compute)
      stageK((kt & 1) ? Ks0 : Qs, kt + 1);
      stageV((kt & 1) ? Vt0 : Vt1, kt + 1);
    }
    // mask words for this lane's 4 rows (issue early, overlap latency)
    u32 mw0[4], mw1[4];
#pragma unroll
    for (int r = 0; r < 4; r++) {
      int q = q0 + w * 16 + rq0 + r;
      mw0[r] = mb[(size_t)(b * Sq + q) * 32 + kt * 2];
      mw1[r] = mb[(size_t)(b * Sq + q) * 32 + kt * 2 + 1];
    }

    // QK^T
    f32x4 sc[4];
#pragma unroll
    for (int n = 0; n < 4; n++) sc[n] = (f32x4){0.f, 0.f, 0.f, 0.f};
#pragma unroll
    for (int kk = 0; kk < 2; kk++) {
#pragma unroll
      for (int n = 0; n < 4; n++) {
        int krow = n * 16 + lr;
        bf16x8 kf = *reinterpret_cast<const bf16x8*>(
            &kb[krow * 64 + ((kk * 32 + lkq) ^ ((krow & 7) << 3))]);
        sc[n] = __builtin_amdgcn_mfma_f32_16x16x32_bf16(qf[kk], kf, sc[n], 0, 0, 0);
      }
    }

    // scale + mask (fast path when both words all-ones) + row max
    float rmax[4] = {-1e30f, -1e30f, -1e30f, -1e30f};
#pragma unroll
    for (int r = 0; r < 4; r++) {
      if ((mw0[r] & mw1[r]) == 0xffffffffu) {
#pragma unroll
        for (int n = 0; n < 4; n++) {
          float sval = sc[n][r] * 0.125f;
          sc[n][r] = sval;
          rmax[r] = fmaxf(rmax[r], sval);
        }
      } else {
#pragma unroll
        for (int n = 0; n < 4; n++) {
          int kin = n * 16 + lr;
          float sval = sc[n][r] * 0.125f;
          u32 word = (kin & 32) ? mw1[r] : mw0[r];
          if (!((word >> (kin & 31)) & 1)) sval = -1e9f;
          sc[n][r] = sval;
          rmax[r] = fmaxf(rmax[r], sval);
        }
      }
    }
    // 16-lane-group reduce + defer-max (skip rescale when growth <= 8)
#pragma unroll
    for (int r = 0; r < 4; r++) {
#pragma unroll
      for (int mm = 1; mm < 16; mm <<= 1) rmax[r] = fmaxf(rmax[r], __shfl_xor(rmax[r], mm));
      float mnew = fmaxf(m_i[r], rmax[r]);
      if (mnew - m_i[r] > 8.0f) {
        float scale = __expf(m_i[r] - mnew);
        m_i[r] = mnew;
        l_i[r] *= scale;
#pragma unroll
        for (int n = 0; n < 4; n++) accO[n][r] *= scale;
      }
    }
    float rsum[4] = {0.f, 0.f, 0.f, 0.f};
#pragma unroll
    for (int n = 0; n < 4; n++)
#pragma unroll
      for (int r = 0; r < 4; r++) {
        float p = __expf(sc[n][r] - m_i[r]);
        sc[n][r] = p;
        rsum[r] += p;
      }
#pragma unroll
    for (int r = 0; r < 4; r++) {
#pragma unroll
      for (int mm = 1; mm < 16; mm <<= 1) rsum[r] += __shfl_xor(rsum[r], mm);
      l_i[r] += rsum[r];
    }
    // P -> LDS (per-wave private region, swizzled)
#pragma unroll
    for (int n = 0; n < 4; n++)
#pragma unroll
      for (int r = 0; r < 4; r++) {
        int row = rq0 + r;
        Ps[w * 1024 + row * 64 + ((n * 16 + lr) ^ ((row & 7) << 3))] = f2bf(sc[n][r]);
      }
    asm volatile("s_waitcnt lgkmcnt(0)" ::: "memory");
    __builtin_amdgcn_sched_barrier(0);
    // PV
    bf16x8 pf[2];
#pragma unroll
    for (int kk = 0; kk < 2; kk++)
      pf[kk] = *reinterpret_cast<const bf16x8*>(
          &Ps[w * 1024 + lr * 64 + ((kk * 32 + lkq) ^ ((lr & 7) << 3))]);
#pragma unroll
    for (int kk = 0; kk < 2; kk++) {
#pragma unroll
      for (int n = 0; n < 4; n++) {
        int d = n * 16 + lr;
        bf16x8 vf = *reinterpret_cast<const bf16x8*>(
            &vb[d * 64 + ((kk * 32 + lkq) ^ ((d & 7) << 3))]);
        accO[n] = __builtin_amdgcn_mfma_f32_16x16x32_bf16(pf[kk], vf, accO[n], 0, 0, 0);
      }
    }
    __syncthreads();   // drains vmcnt too: next tile's staged data ready
  }

#pragma unroll
  for (int r = 0; r < 4; r++) {
    float recip = (m_i[r] <= -0.9e9f || l_i[r] == 0.f) ? 0.f : 1.f / l_i[r];
    int grow = q0 + w * 16 + rq0 + r;
#pragma unroll
    for (int n = 0; n < 4; n++)
      ctxb[(size_t)(b * Sq + grow) * Dm + h * 64 + n * 16 + lr] = f2bf(accO[n][r] * recip);
  }
}

// ---------------- launch ----------------
extern "C" void kernel_launch(void* const* d_in, const int* in_sizes, int n_in,
                              void* d_out, int out_size, void* d_ws, size_t ws_size,
                              hipStream_t stream) {
  const float* x     = (const float*)d_in[0];
  const float* Wq    = (const float*)d_in[1];
  const float* Wk    = (const float*)d_in[2];
  const float* Wv    = (const float*)d_in[3];
  const float* Wo    = (const float*)d_in[4];
  const float* w1    = (const float*)d_in[5];
  const float* b1    = (const float*)d_in[6];
  const float* w2    = (const float*)d_in[7];
  const float* b2    = (const float*)d_in[8];
  const float* ln1g  = (const float*)d_in[9];
  const float* ln1b  = (const float*)d_in[10];
  const float* ln2g  = (const float*)d_in[11];
  const float* ln2b  = (const float*)d_in[12];
  const int*   mask  = (const int*)d_in[13];
  float* out = (float*)d_out;

  char* ws = (char*)d_ws;
  const size_t MB = 1024 * 1024;
  u16* wqkv_b = (u16*)(ws + 0 * MB);
  u16* wo_b   = (u16*)(ws + 13 * MB / 2);
  u16* w1_b   = (u16*)(ws + 17 * MB / 2);
  u16* w2_b   = (u16*)(ws + 17 * MB);
  u16* h_b    = (u16*)(ws + 51 * MB / 2);
  u32* mbits  = (u32*)(ws + 34 * MB);
  u32* rv     = (u32*)(ws + 34 * MB + 600 * 1024);
  u16* qkv    = (u16*)(ws + 35 * MB);
  u16* ctxb   = (u16*)(ws + 121 * MB / 2);
  u16* vTb    = (u16*)(ws + 69 * MB);
  u16* a1b    = (u16*)(ws + 35 * MB);
  float* x1   = out;   // attention-sublayer result lives in d_out (in-place resid for w2)

  k_cvt<<<1024, 256, 0, stream>>>(Wq, wqkv_b,               262144);
  k_cvt<<<1024, 256, 0, stream>>>(Wk, wqkv_b + 1024 * 1024, 262144);
  k_cvt<<<1024, 256, 0, stream>>>(Wv, wqkv_b + 2048 * 1024, 262144);
  k_cvt<<<1024, 256, 0, stream>>>(Wo, wo_b, 262144);
  k_cvt<<<4096, 256, 0, stream>>>(w1, w1_b, 1048576);
  k_cvt<<<4096, 256, 0, stream>>>(w2, w2_b, 1048576);
  k_maskpack<<<4096, 256, 0, stream>>>(mask, mbits, rv);
  k_ln<<<4096, 256, 0, stream>>>(x, ln1g, ln1b, h_b);

  // fused QKV: M=4096, N=3072, K=1024 -> 768 blocks (3/CU)
  dim3 gqkv(QS / 128, Mtok / 128);
  k_gemm<0><<<gqkv, 256, 0, stream>>>(h_b, wqkv_b, Mtok, QS, Dm, nullptr, qkv);

  // V transpose for attn: 1024 blocks, coalesced both sides
  dim3 gvt(Sq / 64, Bz * Hn);
  k_vtrans<<<gvt, 256, 0, stream>>>(qkv, vTb);

  dim3 ga(Sq / 64, Bz * Hn);
  k_attn<<<ga, 256, 0, stream>>>(qkv, vTb, mbits, ctxb);

  // Wo: M=4096, N=1024, K=1024 -> (16,32) = 512 blocks (2/CU)
  dim3 gwo(Dm / 64, Mtok / 128);
  k_gemm64<1><<<gwo, 256, 0, stream>>>(ctxb, wo_b, Mtok, Dm, Dm, x, nullptr, nullptr, x1);

  k_ln<<<4096, 256, 0, stream>>>(x1, ln2g, ln2b, h_b);

  // w1: M=4096, N=4096, K=1024 -> 1024 blocks (4/CU)
  dim3 g2(Ff / 128, Mtok / 128);
  k_gemm<2><<<g2, 256, 0, stream>>>(h_b, w1_b, Mtok, Ff, Dm, b1, a1b);

  // w2: M=4096, N=1024, K=4096 -> (16,32) = 512 blocks (2/CU)
  dim3 gw2(Dm / 64, Mtok / 128);
  k_gemm64<3><<<gw2, 256, 0, stream>>>(a1b, w2_b, Mtok, Dm, Ff, x1, b2, rv, out);
}

// Round 12
// 388.154 us; speedup vs baseline: 1.4193x; 1.1108x over previous
//
#include <hip/hip_runtime.h>

typedef unsigned short u16;
typedef unsigned int   u32;
typedef unsigned long long u64;

typedef __bf16 bf16_t;
typedef bf16_t bf16x8 __attribute__((ext_vector_type(8)));
typedef float  f32x4  __attribute__((ext_vector_type(4)));

static constexpr int Bz = 4, Sq = 1024, Dm = 1024, Hn = 16, Ff = 4096, Mtok = 4096;
static constexpr int QS = 3072;   // fused qkv row stride

static __device__ __forceinline__ u16 f2bf(float f) {
  u32 u = __builtin_bit_cast(u32, f);
  u32 r = u + 0x7fff + ((u >> 16) & 1);
  return (u16)(r >> 16);
}

static __device__ __forceinline__ void gld16(const u16* g, u16* l) {
  __builtin_amdgcn_global_load_lds((const __attribute__((address_space(1))) u32*)g,
                                   (__attribute__((address_space(3))) u32*)l, 16, 0, 0);
}

// ---------------- fp32 -> bf16 cast ----------------
__global__ void k_cvt(const float* __restrict__ src, u16* __restrict__ dst, int n4) {
  int i = blockIdx.x * 256 + threadIdx.x;
  if (i >= n4) return;
  float4 v = reinterpret_cast<const float4*>(src)[i];
  ushort4 o;
  o.x = f2bf(v.x); o.y = f2bf(v.y); o.z = f2bf(v.z); o.w = f2bf(v.w);
  reinterpret_cast<ushort4*>(dst)[i] = o;
}

// ---------------- mask -> bitmask + row_valid ----------------
__global__ void k_maskpack(const int* __restrict__ mask, u32* __restrict__ mb,
                           u32* __restrict__ rv) {
  int row = blockIdx.x;
  int t = threadIdx.x, w = t >> 6, lane = t & 63;
  const int* mrow = mask + (size_t)row * Sq;
  __shared__ u32 red[4];
  u32 any = 0;
#pragma unroll
  for (int i = 0; i < 4; i++) {
    int chunk = w * 4 + i;
    int k = chunk * 64 + lane;
    u64 bal = __ballot(mrow[k] != 0);
    any |= (u32)(bal | (bal >> 32));
    if (lane == 0) mb[(size_t)row * 32 + chunk * 2]     = (u32)bal;
    if (lane == 1) mb[(size_t)row * 32 + chunk * 2 + 1] = (u32)(bal >> 32);
  }
  if (lane == 0) red[w] = any;
  __syncthreads();
  if (t == 0) rv[row] = (red[0] | red[1] | red[2] | red[3]) ? 1u : 0u;
}

// ---------------- LayerNorm (one block per row) -> bf16 ----------------
__global__ void k_ln(const float* __restrict__ x, const float* __restrict__ g,
                     const float* __restrict__ bb, u16* __restrict__ out) {
  int row = blockIdx.x, t = threadIdx.x;
  float4 v = reinterpret_cast<const float4*>(x + (size_t)row * Dm)[t];
  float s  = v.x + v.y + v.z + v.w;
  float s2 = v.x * v.x + v.y * v.y + v.z * v.z + v.w * v.w;
#pragma unroll
  for (int m = 1; m < 64; m <<= 1) { s += __shfl_xor(s, m); s2 += __shfl_xor(s2, m); }
  __shared__ float rs[4], rs2[4];
  int w = t >> 6;
  if ((t & 63) == 0) { rs[w] = s; rs2[w] = s2; }
  __syncthreads();
  s  = rs[0] + rs[1] + rs[2] + rs[3];
  s2 = rs2[0] + rs2[1] + rs2[2] + rs2[3];
  float mu  = s * (1.0f / Dm);
  float var = s2 * (1.0f / Dm) - mu * mu;
  float r = rsqrtf(var + 1e-5f);
  float4 gv = reinterpret_cast<const float4*>(g)[t];
  float4 bv = reinterpret_cast<const float4*>(bb)[t];
  ushort4 o;
  o.x = f2bf((v.x - mu) * r * gv.x + bv.x);
  o.y = f2bf((v.y - mu) * r * gv.y + bv.y);
  o.z = f2bf((v.z - mu) * r * gv.z + bv.z);
  o.w = f2bf((v.w - mu) * r * gv.w + bv.w);
  reinterpret_cast<ushort4*>(out + (size_t)row * Dm)[t] = o;
}

// ---------------- GEMM 128x128: C[M,N] = A[M,K] * Bw[N,K]^T ----------------
// T2 LDS swizzle + bijective XCD swizzle.
// MODE 0: store bf16 (cols < 1024 scaled by 0.125 = 1/sqrt(DK), Q pre-scale)
// MODE 2: bf16 out = gelu(acc + bias)
template <int MODE>
__global__ __launch_bounds__(256)
void k_gemm(const u16* __restrict__ A, const u16* __restrict__ Bw,
            int M, int N, int K,
            const float* __restrict__ bias, void* __restrict__ Cout) {
  __shared__ u16 As[128 * 64];
  __shared__ u16 Bs[128 * 64];
  const int t = threadIdx.x;
  const int lane = t & 63, w = t >> 6;
  const int wr = w >> 1, wc = w & 1;
  const int nx = gridDim.x;
  const int nwg = nx * gridDim.y;
  const int bid = blockIdx.y * nx + blockIdx.x;
  const int swz = (bid & 7) * (nwg >> 3) + (bid >> 3);
  const int m0 = (swz / nx) * 128, n0 = (swz % nx) * 128;
  const int lr = lane & 15, lk = (lane >> 4) * 8;

  f32x4 acc[4][4] = {};

  for (int kt = 0; kt < K; kt += 64) {
#pragma unroll
    for (int i = 0; i < 4; i++) {
      int cc = i * 256 + t; int row = cc >> 3, c8 = cc & 7;
      gld16(A + (size_t)(m0 + row) * K + kt + ((c8 ^ (row & 7)) * 8), &As[cc * 8]);
    }
#pragma unroll
    for (int i = 0; i < 4; i++) {
      int cc = i * 256 + t; int row = cc >> 3, c8 = cc & 7;
      gld16(Bw + (size_t)(n0 + row) * K + kt + ((c8 ^ (row & 7)) * 8), &Bs[cc * 8]);
    }
    __syncthreads();
#pragma unroll
    for (int kk = 0; kk < 2; kk++) {
      bf16x8 af[4], bfg[4];
#pragma unroll
      for (int m = 0; m < 4; m++) {
        int row = wr * 64 + m * 16 + lr;
        af[m] = *reinterpret_cast<const bf16x8*>(
            &As[row * 64 + ((kk * 32 + lk) ^ ((row & 7) << 3))]);
      }
#pragma unroll
      for (int n = 0; n < 4; n++) {
        int row = wc * 64 + n * 16 + lr;
        bfg[n] = *reinterpret_cast<const bf16x8*>(
            &Bs[row * 64 + ((kk * 32 + lk) ^ ((row & 7) << 3))]);
      }
#pragma unroll
      for (int m = 0; m < 4; m++)
#pragma unroll
        for (int n = 0; n < 4; n++)
          acc[m][n] = __builtin_amdgcn_mfma_f32_16x16x32_bf16(af[m], bfg[n], acc[m][n], 0, 0, 0);
    }
    __syncthreads();
  }

  const float qscale = (MODE == 0 && n0 < 1024) ? 0.125f : 1.0f;
#pragma unroll
  for (int m = 0; m < 4; m++) {
    const int rowb = m0 + wr * 64 + m * 16 + (lane >> 4) * 4;
#pragma unroll
    for (int n = 0; n < 4; n++) {
      const int col = n0 + wc * 64 + n * 16 + lr;
#pragma unroll
      for (int r = 0; r < 4; r++) {
        const int row = rowb + r;
        float v = acc[m][n][r];
        size_t idx = (size_t)row * N + col;
        if constexpr (MODE == 0) {
          ((u16*)Cout)[idx] = f2bf(v * qscale);
        } else {
          float xx = v + bias[col];
          float gl = 0.5f * xx * (1.0f + erff(xx * 0.70710678118f));
          ((u16*)Cout)[idx] = f2bf(gl);
        }
      }
    }
  }
}

// ---------------- GEMM BM128xBN64xBK64 (N=1024 shapes) ----------
// T2 LDS swizzle + bijective XCD swizzle.
// MODE 1: f32 out = resid + acc
// MODE 3: f32 out = resid + (rv[row] ? acc + bias : 0)
template <int MODE>
__global__ __launch_bounds__(256)
void k_gemm64(const u16* __restrict__ A, const u16* __restrict__ Bw,
              int M, int N, int K,
              const float* __restrict__ resid, const float* __restrict__ bias,
              const u32* __restrict__ rv, float* __restrict__ Cout) {
  __shared__ u16 As[128 * 64];
  __shared__ u16 Bs[64 * 64];
  const int t = threadIdx.x;
  const int lane = t & 63, w = t >> 6;
  const int nx = gridDim.x;
  const int nwg = nx * gridDim.y;
  const int bid = blockIdx.y * nx + blockIdx.x;
  const int swz = (bid & 7) * (nwg >> 3) + (bid >> 3);
  const int n0 = (swz % nx) * 64, m0 = (swz / nx) * 128;
  const int lr = lane & 15, lk = (lane >> 4) * 8;

  f32x4 acc[2][4] = {};

  for (int kt = 0; kt < K; kt += 64) {
#pragma unroll
    for (int i = 0; i < 4; i++) {
      int cc = i * 256 + t; int row = cc >> 3, c8 = cc & 7;
      gld16(A + (size_t)(m0 + row) * K + kt + ((c8 ^ (row & 7)) * 8), &As[cc * 8]);
    }
#pragma unroll
    for (int i = 0; i < 2; i++) {
      int cc = i * 256 + t; int row = cc >> 3, c8 = cc & 7;
      gld16(Bw + (size_t)(n0 + row) * K + kt + ((c8 ^ (row & 7)) * 8), &Bs[cc * 8]);
    }
    __syncthreads();
#pragma unroll
    for (int kk = 0; kk < 2; kk++) {
      bf16x8 af[2], bfg[4];
#pragma unroll
      for (int m = 0; m < 2; m++) {
        int row = w * 32 + m * 16 + lr;
        af[m] = *reinterpret_cast<const bf16x8*>(
            &As[row * 64 + ((kk * 32 + lk) ^ ((row & 7) << 3))]);
      }
#pragma unroll
      for (int n = 0; n < 4; n++) {
        int row = n * 16 + lr;
        bfg[n] = *reinterpret_cast<const bf16x8*>(
            &Bs[row * 64 + ((kk * 32 + lk) ^ ((row & 7) << 3))]);
      }
#pragma unroll
      for (int m = 0; m < 2; m++)
#pragma unroll
        for (int n = 0; n < 4; n++)
          acc[m][n] = __builtin_amdgcn_mfma_f32_16x16x32_bf16(af[m], bfg[n], acc[m][n], 0, 0, 0);
    }
    __syncthreads();
  }

#pragma unroll
  for (int m = 0; m < 2; m++) {
    const int rowb = m0 + w * 32 + m * 16 + (lane >> 4) * 4;
#pragma unroll
    for (int n = 0; n < 4; n++) {
      const int col = n0 + n * 16 + lr;
#pragma unroll
      for (int r = 0; r < 4; r++) {
        const int row = rowb + r;
        float v = acc[m][n][r];
        size_t idx = (size_t)row * N + col;
        if constexpr (MODE == 1) {
          Cout[idx] = resid[idx] + v;
        } else {
          float y = rv[row] ? (v + bias[col]) : 0.0f;
          Cout[idx] = resid[idx] + y;
        }
      }
    }
  }
}

// ---------------- V transpose: qkv V-cols -> vT[bh][d][tok] ----------------
__global__ __launch_bounds__(256)
void k_vtrans(const u16* __restrict__ qkv, u16* __restrict__ vT) {
  __shared__ u16 tile[64 * 72];
  const int t = threadIdx.x;
  const int tt = blockIdx.x;
  const int bh = blockIdx.y, b = bh >> 4, h = bh & 15;
  const u16* src = qkv + (size_t)(b * Sq + tt * 64) * QS + 2048 + h * 64;
#pragma unroll
  for (int j = 0; j < 2; j++) {
    int cc = j * 256 + t, row = cc >> 3, dc0 = (cc & 7) * 8;
    uint4 v = *reinterpret_cast<const uint4*>(src + (size_t)row * QS + dc0);
    *reinterpret_cast<uint4*>(&tile[row * 72 + dc0]) = v;
  }
  __syncthreads();
#pragma unroll
  for (int j = 0; j < 2; j++) {
    int cc = j * 256 + t, d = cc >> 3, tk0 = (cc & 7) * 8;
    u16 tmp[8];
#pragma unroll
    for (int e = 0; e < 8; e++) tmp[e] = tile[(tk0 + e) * 72 + d];
    *reinterpret_cast<uint4*>(vT + (size_t)bh * 65536 + (size_t)d * 1024 + tt * 64 + tk0) =
        *reinterpret_cast<uint4*>(tmp);
  }
}

// ---------------- Flash attention v3 ----------------
// Q pre-scaled by 0.125 in QKV epilogue. T13 defer-max with __any fast path,
// per-lane partial l (reduced once at end), native bf16 cvt for Ps, XCD swizzle
// (same-bh blocks -> same XCD for K/vT L2 reuse).
__global__ __launch_bounds__(256)
void k_attn(const u16* __restrict__ qkv, const u16* __restrict__ vT,
            const u32* __restrict__ mb, u16* __restrict__ ctxb) {
  __shared__ u16 Qs[4096];    // doubles as K buf 1
  __shared__ u16 Ks0[4096];
  __shared__ u16 Vt0[4096];
  __shared__ u16 Vt1[4096];
  __shared__ u16 Ps[4096];
  const int t = threadIdx.x, lane = t & 63, w = t >> 6;
  // XCD swizzle: nwg = 1024; each XCD gets 128 consecutive swz = 8 bh x 16 q-tiles
  const int bid = blockIdx.y * gridDim.x + blockIdx.x;
  const int nwg = gridDim.x * gridDim.y;
  const int swz = (bid & 7) * (nwg >> 3) + (bid >> 3);
  const int q0 = (swz & 15) * 64;
  const int bh = swz >> 4, b = bh >> 4, h = bh & 15;
  const int lr = lane & 15, lkq = (lane >> 4) * 8;

  const size_t qbase = (size_t)(b * Sq + q0) * QS + h * 64;
  const size_t kbase = (size_t)(b * Sq) * QS + 1024 + h * 64;
  const size_t vbase = (size_t)bh * 65536;

  auto stageK = [&](u16* dst, int kt) {
#pragma unroll
    for (int j = 0; j < 2; j++) {
      int cc = j * 256 + t, r = cc >> 3, ch = cc & 7;
      gld16(qkv + kbase + (size_t)(kt * 64 + r) * QS + ((ch ^ (r & 7)) * 8), dst + cc * 8);
    }
  };
  auto stageV = [&](u16* dst, int kt) {
#pragma unroll
    for (int j = 0; j < 2; j++) {
      int cc = j * 256 + t, d = cc >> 3, ch = cc & 7;
      gld16(vT + vbase + (size_t)d * 1024 + kt * 64 + ((ch ^ (d & 7)) * 8), dst + cc * 8);
    }
  };

  // prologue: stage Q + tile 0
  {
#pragma unroll
    for (int j = 0; j < 2; j++) {
      int cc = j * 256 + t, r = cc >> 3, ch = cc & 7;
      gld16(qkv + qbase + (size_t)r * QS + ((ch ^ (r & 7)) * 8), &Qs[cc * 8]);
    }
  }
  stageK(Ks0, 0);
  stageV(Vt0, 0);
  __syncthreads();

  bf16x8 qf[2];
  const int qrow = w * 16 + lr;
#pragma unroll
  for (int kk = 0; kk < 2; kk++)
    qf[kk] = *reinterpret_cast<const bf16x8*>(&Qs[qrow * 64 + ((kk * 32 + lkq) ^ ((qrow & 7) << 3))]);
  __syncthreads();   // Qs now free for reuse as K buf 1

  float m_i[4] = {-1e30f, -1e30f, -1e30f, -1e30f};
  float l_i[4] = {0.f, 0.f, 0.f, 0.f};   // per-lane PARTIAL row sums (4 cols each)
  f32x4 accO[4] = {};
  const int rq0 = (lane >> 4) * 4;

  for (int kt = 0; kt < Sq / 64; kt++) {
    u16* kb = (kt & 1) ? Qs : Ks0;
    u16* vb = (kt & 1) ? Vt1 : Vt0;
    if (kt + 1 < Sq / 64) {
      stageK((kt & 1) ? Ks0 : Qs, kt + 1);
      stageV((kt & 1) ? Vt0 : Vt1, kt + 1);
    }
    u32 mw0[4], mw1[4];
#pragma unroll
    for (int r = 0; r < 4; r++) {
      int q = q0 + w * 16 + rq0 + r;
      mw0[r] = mb[(size_t)(b * Sq + q) * 32 + kt * 2];
      mw1[r] = mb[(size_t)(b * Sq + q) * 32 + kt * 2 + 1];
    }

    // QK^T (Q already carries the 1/sqrt(DK) scale)
    f32x4 sc[4];
#pragma unroll
    for (int n = 0; n < 4; n++) sc[n] = (f32x4){0.f, 0.f, 0.f, 0.f};
#pragma unroll
    for (int kk = 0; kk < 2; kk++) {
#pragma unroll
      for (int n = 0; n < 4; n++) {
        int krow = n * 16 + lr;
        bf16x8 kf = *reinterpret_cast<const bf16x8*>(
            &kb[krow * 64 + ((kk * 32 + lkq) ^ ((krow & 7) << 3))]);
        sc[n] = __builtin_amdgcn_mfma_f32_16x16x32_bf16(qf[kk], kf, sc[n], 0, 0, 0);
      }
    }

    // mask + per-lane partial max (no shuffle in fast path)
    float pmax[4] = {-1e30f, -1e30f, -1e30f, -1e30f};
#pragma unroll
    for (int r = 0; r < 4; r++) {
      if ((mw0[r] & mw1[r]) == 0xffffffffu) {
#pragma unroll
        for (int n = 0; n < 4; n++) pmax[r] = fmaxf(pmax[r], sc[n][r]);
      } else {
#pragma unroll
        for (int n = 0; n < 4; n++) {
          int kin = n * 16 + lr;
          u32 word = (kin & 32) ? mw1[r] : mw0[r];
          float sval = sc[n][r];
          if (!((word >> (kin & 31)) & 1)) sval = -1e9f;
          sc[n][r] = sval;
          pmax[r] = fmaxf(pmax[r], sval);
        }
      }
    }
    // T13 defer-max: rescale only when some row grew > THR (wave-uniform branch)
    int need = 0;
#pragma unroll
    for (int r = 0; r < 4; r++) need |= (pmax[r] - m_i[r] > 8.0f) ? 1 : 0;
    if (__any(need)) {
#pragma unroll
      for (int r = 0; r < 4; r++) {
        float rmax = pmax[r];
#pragma unroll
        for (int mm = 1; mm < 16; mm <<= 1) rmax = fmaxf(rmax, __shfl_xor(rmax, mm));
        float mnew = fmaxf(m_i[r], rmax);
        float scale = __expf(m_i[r] - mnew);
        m_i[r] = mnew;
        l_i[r] *= scale;
#pragma unroll
        for (int n = 0; n < 4; n++) accO[n][r] *= scale;
      }
    }
    // exp + partial l + P -> LDS (native bf16 cvt)
#pragma unroll
    for (int n = 0; n < 4; n++)
#pragma unroll
      for (int r = 0; r < 4; r++) {
        float p = __expf(sc[n][r] - m_i[r]);
        l_i[r] += p;
        int row = rq0 + r;
        Ps[w * 1024 + row * 64 + ((n * 16 + lr) ^ ((row & 7) << 3))] =
            __builtin_bit_cast(u16, (bf16_t)p);
      }
    asm volatile("s_waitcnt lgkmcnt(0)" ::: "memory");
    __builtin_amdgcn_sched_barrier(0);
    // PV
    bf16x8 pf[2];
#pragma unroll
    for (int kk = 0; kk < 2; kk++)
      pf[kk] = *reinterpret_cast<const bf16x8*>(
          &Ps[w * 1024 + lr * 64 + ((kk * 32 + lkq) ^ ((lr & 7) << 3))]);
#pragma unroll
    for (int kk = 0; kk < 2; kk++) {
#pragma unroll
      for (int n = 0; n < 4; n++) {
        int d = n * 16 + lr;
        bf16x8 vf = *reinterpret_cast<const bf16x8*>(
            &vb[d * 64 + ((kk * 32 + lkq) ^ ((d & 7) << 3))]);
        accO[n] = __builtin_amdgcn_mfma_f32_16x16x32_bf16(pf[kk], vf, accO[n], 0, 0, 0);
      }
    }
    __syncthreads();
  }

  // final: reduce the per-lane partial l across the 16-lane column group
#pragma unroll
  for (int r = 0; r < 4; r++) {
#pragma unroll
    for (int mm = 1; mm < 16; mm <<= 1) l_i[r] += __shfl_xor(l_i[r], mm);
  }

#pragma unroll
  for (int r = 0; r < 4; r++) {
    float recip = (m_i[r] <= -0.9e9f || l_i[r] == 0.f) ? 0.f : 1.f / l_i[r];
    int grow = q0 + w * 16 + rq0 + r;
#pragma unroll
    for (int n = 0; n < 4; n++)
      ctxb[(size_t)(b * Sq + grow) * Dm + h * 64 + n * 16 + lr] = f2bf(accO[n][r] * recip);
  }
}

// ---------------- launch ----------------
extern "C" void kernel_launch(void* const* d_in, const int* in_sizes, int n_in,
                              void* d_out, int out_size, void* d_ws, size_t ws_size,
                              hipStream_t stream) {
  const float* x     = (const float*)d_in[0];
  const float* Wq    = (const float*)d_in[1];
  const float* Wk    = (const float*)d_in[2];
  const float* Wv    = (const float*)d_in[3];
  const float* Wo    = (const float*)d_in[4];
  const float* w1    = (const float*)d_in[5];
  const float* b1    = (const float*)d_in[6];
  const float* w2    = (const float*)d_in[7];
  const float* b2    = (const float*)d_in[8];
  const float* ln1g  = (const float*)d_in[9];
  const float* ln1b  = (const float*)d_in[10];
  const float* ln2g  = (const float*)d_in[11];
  const float* ln2b  = (const float*)d_in[12];
  const int*   mask  = (const int*)d_in[13];
  float* out = (float*)d_out;

  char* ws = (char*)d_ws;
  const size_t MB = 1024 * 1024;
  u16* wqkv_b = (u16*)(ws + 0 * MB);
  u16* wo_b   = (u16*)(ws + 13 * MB / 2);
  u16* w1_b   = (u16*)(ws + 17 * MB / 2);
  u16* w2_b   = (u16*)(ws + 17 * MB);
  u16* h_b    = (u16*)(ws + 51 * MB / 2);
  u32* mbits  = (u32*)(ws + 34 * MB);
  u32* rv     = (u32*)(ws + 34 * MB + 600 * 1024);
  u16* qkv    = (u16*)(ws + 35 * MB);
  u16* ctxb   = (u16*)(ws + 121 * MB / 2);
  u16* vTb    = (u16*)(ws + 69 * MB);
  u16* a1b    = (u16*)(ws + 35 * MB);
  float* x1   = out;   // attention-sublayer result lives in d_out (in-place resid for w2)

  k_cvt<<<1024, 256, 0, stream>>>(Wq, wqkv_b,               262144);
  k_cvt<<<1024, 256, 0, stream>>>(Wk, wqkv_b + 1024 * 1024, 262144);
  k_cvt<<<1024, 256, 0, stream>>>(Wv, wqkv_b + 2048 * 1024, 262144);
  k_cvt<<<1024, 256, 0, stream>>>(Wo, wo_b, 262144);
  k_cvt<<<4096, 256, 0, stream>>>(w1, w1_b, 1048576);
  k_cvt<<<4096, 256, 0, stream>>>(w2, w2_b, 1048576);
  k_maskpack<<<4096, 256, 0, stream>>>(mask, mbits, rv);
  k_ln<<<4096, 256, 0, stream>>>(x, ln1g, ln1b, h_b);

  // fused QKV: M=4096, N=3072, K=1024 -> 768 blocks (3/CU); Q cols pre-scaled
  dim3 gqkv(QS / 128, Mtok / 128);
  k_gemm<0><<<gqkv, 256, 0, stream>>>(h_b, wqkv_b, Mtok, QS, Dm, nullptr, qkv);

  dim3 gvt(Sq / 64, Bz * Hn);
  k_vtrans<<<gvt, 256, 0, stream>>>(qkv, vTb);

  dim3 ga(Sq / 64, Bz * Hn);
  k_attn<<<ga, 256, 0, stream>>>(qkv, vTb, mbits, ctxb);

  // Wo: M=4096, N=1024, K=1024 -> (16,32) = 512 blocks (2/CU)
  dim3 gwo(Dm / 64, Mtok / 128);
  k_gemm64<1><<<gwo, 256, 0, stream>>>(ctxb, wo_b, Mtok, Dm, Dm, x, nullptr, nullptr, x1);

  k_ln<<<4096, 256, 0, stream>>>(x1, ln2g, ln2b, h_b);

  // w1: M=4096, N=4096, K=1024 -> 1024 blocks (4/CU)
  dim3 g2(Ff / 128, Mtok / 128);
  k_gemm<2><<<g2, 256, 0, stream>>>(h_b, w1_b, Mtok, Ff, Dm, b1, a1b);

  // w2: M=4096, N=1024, K=4096 -> (16,32) = 512 blocks (2/CU)
  dim3 gw2(Dm / 64, Mtok / 128);
  k_gemm64<3><<<gw2, 256, 0, stream>>>(a1b, w2_b, Mtok, Dm, Ff, x1, b2, rv, out);
}